// Round 5
// baseline (192.550 us; speedup 1.0000x reference)
//
#include <hip/hip_runtime.h>
#include <hip/hip_bf16.h>
#include <stdint.h>

#define SEQ 2048
#define NB 4
#define NH 12
#define DMODEL 768
#define DK 64
#define NTOK (NB*SEQ)          // 8192
#define QSCALE 0.18033688011f  // 0.125 * log2(e)

#define N_X4   (NTOK*DMODEL/4)          // 1572864
#define N_WQ4  (3*DMODEL*DMODEL/4)      // 442368
#define N_WO4  (DMODEL*DMODEL/4)        // 147456

typedef __bf16 bf16_t;
typedef __attribute__((ext_vector_type(4))) bf16_t bf16x4;
typedef __attribute__((ext_vector_type(8))) bf16_t bf16x8;
typedef __attribute__((ext_vector_type(4))) float f32x4;

typedef __attribute__((address_space(3))) uint32_t lds_u32_t;
typedef const __attribute__((address_space(1))) uint32_t glb_u32_t;

__device__ inline void load_lds16(const void* g, void* l) {
    __builtin_amdgcn_global_load_lds((glb_u32_t*)g, (lds_u32_t*)l, 16, 0, 0);
}

// ---------------- fp32 -> bf16 convert (x, wqkv, wo fused; dst regions contiguous) ----------------
__global__ void cvt_all(const float* __restrict__ x, const float* __restrict__ wq,
                        const float* __restrict__ wo, bf16_t* __restrict__ dst) {
    int i = blockIdx.x * blockDim.x + threadIdx.x;   // grid sized exactly
    const float* src; int off;
    if (i < N_X4)              { src = x;  off = i; }
    else if (i < N_X4 + N_WQ4) { src = wq; off = i - N_X4; }
    else                       { src = wo; off = i - (N_X4 + N_WQ4); }
    float4 v = ((const float4*)src)[off];
    bf16x4 o;
    o[0] = (bf16_t)v.x; o[1] = (bf16_t)v.y; o[2] = (bf16_t)v.z; o[3] = (bf16_t)v.w;
    ((bf16x4*)dst)[i] = o;
}

// =================== QKV GEMM: 128x192 tile, BK=32, dbuf, R13 line-pair XOR-swizzled LDS ===================
// R14 note: bank conflicts measured 0 after the R13 swizzle; dur unchanged -> 2-phase structural
// ceiling (~685 TF) reached; conflicts were hidden under the stage/barrier critical path. Keep as-is.
#define QSTAGE(AS, BS, KB) do { \
    _Pragma("unroll") \
    for (int j = 0; j < 5; j++) { \
        int c = tid + j*256; \
        if (c < 512) { \
            int row = c >> 2, cb = ((c & 3) ^ ((c >> 3) & 3)) * 8; \
            load_lds16(Ap_ + (size_t)(mt*128 + row)*DMODEL + (KB) + cb, AS + c*8); \
        } else { \
            int c2 = c - 512; \
            int row = c2 >> 2, cb = ((c2 & 3) ^ ((c2 >> 3) & 3)) * 8; \
            load_lds16(Bp_ + (size_t)(nt*192 + row)*DMODEL + (KB) + cb, BS + c2*8); \
        } \
    } \
} while (0)

#define QCOMPUTE(AS, BS) do { \
    bf16x8 af[4]; \
    _Pragma("unroll") \
    for (int f = 0; f < 4; f++) \
        af[f] = *(const bf16x8*)(AS + (wy*32 + f*8 + lh)*64 + xr); \
    _Pragma("unroll") \
    for (int fn = 0; fn < 6; fn++) { \
        bf16x8 bfr = *(const bf16x8*)(BS + (wx*48 + fn*8 + lh)*64 + xr); \
        _Pragma("unroll") \
        for (int fm = 0; fm < 4; fm++) \
            acc[fm][fn] = __builtin_amdgcn_mfma_f32_16x16x32_bf16(af[fm], bfr, acc[fm][fn], 0, 0, 0); \
    } \
} while (0)

__global__ __launch_bounds__(256, 3) void gemm_qkv(
    const bf16_t* __restrict__ Ap_, const bf16_t* __restrict__ Bp_,
    bf16_t* __restrict__ Qo, bf16_t* __restrict__ Ko, bf16_t* __restrict__ VTo)
{
    __shared__ bf16_t As0[128*32];
    __shared__ bf16_t Bs0[192*32];
    __shared__ bf16_t As1[128*32];
    __shared__ bf16_t Bs1[192*32];
    const int mt = blockIdx.x, nt = blockIdx.y;
    const int tid = threadIdx.x;
    const int w = tid >> 6, lane = tid & 63;
    const int wx = w & 1, wy = w >> 1;
    const int lr = lane & 15, lq = lane >> 4;
    const int lh = lr >> 1;                                  // line index within 16-row group
    const int xr = (lr & 1)*32 + ((lq ^ (lh & 3)) * 8);      // intra-line swizzled elem offset

    f32x4 acc[4][6] = {};
    QSTAGE(As0, Bs0, 0);
    for (int kb = 0; kb < DMODEL; kb += 64) {
        __syncthreads();
        QSTAGE(As1, Bs1, kb + 32);
        QCOMPUTE(As0, Bs0);
        __syncthreads();
        if (kb + 64 < DMODEL) QSTAGE(As0, Bs0, kb + 64);
        QCOMPUTE(As1, Bs1);
    }

    const int t = nt >> 2;                      // 768 = 4*192: tile never spans Q/K/V
    const int ob = (nt & 3) * 192 + wx * 96;    // col base within 768
    if (t == 2) {
        // V: r=0..3 are s-contiguous -> packed b64 stores
        #pragma unroll
        for (int fm = 0; fm < 4; fm++)
            #pragma unroll
            for (int fn = 0; fn < 6; fn++) {
                int m0 = mt*128 + wy*64 + fm*16 + lq*4;
                int o = ob + fn*16 + lr;
                int b = m0 >> 11, s0 = m0 & 2047;
                int h = o >> 6, dk = o & 63;
                bf16x4 v4;
                #pragma unroll
                for (int r = 0; r < 4; r++) v4[r] = (bf16_t)acc[fm][fn][r];
                *(bf16x4*)(VTo + (size_t)((b*NH + h)*DK + dk)*SEQ + s0) = v4;
            }
    } else {
        #pragma unroll
        for (int fm = 0; fm < 4; fm++)
            #pragma unroll
            for (int fn = 0; fn < 6; fn++)
                #pragma unroll
                for (int r = 0; r < 4; r++) {
                    int m = mt*128 + wy*64 + fm*16 + lq*4 + r;
                    int o = ob + fn*16 + lr;
                    int b = m >> 11, s = m & 2047;
                    int h = o >> 6, dk = o & 63;
                    float v = acc[fm][fn][r];
                    if (t == 0) Qo[(size_t)((b*NH + h)*SEQ + s)*DK + dk] = (bf16_t)(v * QSCALE);
                    else        Ko[(size_t)((b*NH + h)*SEQ + s)*DK + dk] = (bf16_t)v;
                }
    }
}

// ---------------- O projection GEMM: 128x64 tile, R13 swizzle, grid (64,12)=768 = 3/CU ----------------
#define OSTAGE(AS, BS, KB) do { \
    _Pragma("unroll") \
    for (int j = 0; j < 3; j++) { \
        int c = tid + j*256; \
        if (c < 512) { \
            int row = c >> 2, cb = ((c & 3) ^ ((c >> 3) & 3)) * 8; \
            load_lds16(Ap_ + (size_t)(mt*128 + row)*DMODEL + (KB) + cb, AS + c*8); \
        } else { \
            int c2 = c - 512; \
            int row = c2 >> 2, cb = ((c2 & 3) ^ ((c2 >> 3) & 3)) * 8; \
            load_lds16(Bp_ + (size_t)(nt*64 + row)*DMODEL + (KB) + cb, BS + c2*8); \
        } \
    } \
} while (0)

#define OCOMPUTE(AS, BS) do { \
    bf16x8 af[4], bfr[2]; \
    _Pragma("unroll") \
    for (int f = 0; f < 4; f++) \
        af[f]  = *(const bf16x8*)(AS + (wy*32 + f*8 + lh)*64 + xr); \
    _Pragma("unroll") \
    for (int f = 0; f < 2; f++) \
        bfr[f] = *(const bf16x8*)(BS + (wx*16 + f*8 + lh)*64 + xr); \
    _Pragma("unroll") \
    for (int fm = 0; fm < 4; fm++) \
        _Pragma("unroll") \
        for (int fn = 0; fn < 2; fn++) \
            acc[fm][fn] = __builtin_amdgcn_mfma_f32_16x16x32_bf16(af[fm], bfr[fn], acc[fm][fn], 0, 0, 0); \
} while (0)

__global__ __launch_bounds__(256, 4) void gemm_oproj(
    const bf16_t* __restrict__ Ap_, const bf16_t* __restrict__ Bp_, float* __restrict__ out)
{
    __shared__ bf16_t As0[128*32];
    __shared__ bf16_t Bs0[64*32];
    __shared__ bf16_t As1[128*32];
    __shared__ bf16_t Bs1[64*32];
    const int mt = blockIdx.x, nt = blockIdx.y;
    const int tid = threadIdx.x;
    const int w = tid >> 6, lane = tid & 63;
    const int wx = w & 1, wy = w >> 1;
    const int lr = lane & 15, lq = lane >> 4;
    const int lh = lr >> 1;
    const int xr = (lr & 1)*32 + ((lq ^ (lh & 3)) * 8);

    f32x4 acc[4][2] = {};
    OSTAGE(As0, Bs0, 0);
    for (int kb = 0; kb < DMODEL; kb += 64) {
        __syncthreads();
        OSTAGE(As1, Bs1, kb + 32);
        OCOMPUTE(As0, Bs0);
        __syncthreads();
        if (kb + 64 < DMODEL) OSTAGE(As0, Bs0, kb + 64);
        OCOMPUTE(As1, Bs1);
    }

    #pragma unroll
    for (int fm = 0; fm < 4; fm++)
        #pragma unroll
        for (int fn = 0; fn < 2; fn++)
            #pragma unroll
            for (int r = 0; r < 4; r++) {
                int m = mt*128 + wy*64 + fm*16 + lq*4 + r;
                int n = nt*64 + wx*32 + fn*16 + lr;
                out[(size_t)m*DMODEL + n] = acc[fm][fn][r];
            }
}

// ---------------- Flash attention (causal) — R15: 128-row q-tile, balanced triple schedule ----------------
// Model (R13/R14 data): attn time tracks LDS fragment traffic (R13: 1.36 strips/frag-read -> 19 µs
// floor, ~38 µs; R14: 1.0 -> 26 µs floor, 49.8 µs; both ~2x floor). R15 maximizes amortization:
// each block owns a 128-row q-tile; every wave runs TWO always-active strips (rows qs, qs+64)
// sharing one bk/bv fragment read -> amortization 2.0, traffic halves vs R13 (floor 13.3 µs).
// Register state identical to R13 (2 acc/al/aq sets, 84 VGPR @ (256,3)); LDS 32 KB; grid 768=3/CU.
// Balance: block lengths nIter = 2*qt2+2 in {2..32}. Co-resident blocks on a CU are {n, n+256,
// n+512} (XCD=n%8, CU=(n/8)%32 linear fill). qt2 assigned per (m=n&255 -> r=(m>>3)&15, slot k=n>>8)
// from 16 triples, each summing 22-24 -> per-CU iters 50-54 (<=1.06x imbalance). Each (bh,qt2)
// appears exactly once; bh = (m&7) + 8*(2*rank+copy) keeps bh%8 == n%8 (XCD K/V locality).
// Tables packed in shift-indexed u64/u32 constants (no runtime-indexed arrays -> no scratch).
// Strips: A rows [128qt2 + w*16), active t < nIter-1, masked at t == nIter-2 (= 2qt2);
// B rows +64, active all t, masked at t == nIter-1. Mask: kl <= w*16 + lr (same as R13 for both).
// K staged with kappa(p) = [p5 p3 p2 p4 p1 p0] so lane (lr,lq)'s 16 score regs are exactly keys
// {lq*8+j} u {32+lq*8+j} = the PV A-fragment octets; P never touches LDS; denominator on MFMA pipe.
#define ASTAGE(KS, VS, KB) do { \
    _Pragma("unroll") \
    for (int j = 0; j < 2; j++) { \
        int rr = w*16 + j*8 + srow; \
        int kperm = (w>>1)*32 + (j*2 + (srow>>2))*8 + (w&1)*4 + (srow&3);  /* kappa(rr) */ \
        load_lds16(Kp + (size_t)((KB) + kperm)*DK + g*8,  &KS[w*1024 + j*512 + lane*8]); \
        load_lds16(Vp + (size_t)rr*SEQ + (KB) + g*8,   &VS[w*1024 + j*512 + lane*8]); \
    } \
} while (0)

#define STRIP(A0, A1, ACC, AL, MASKED) do { \
    f32x4 sc[4]; \
    _Pragma("unroll") \
    for (int ct = 0; ct < 4; ct++) { \
        f32x4 s = {}; \
        s = __builtin_amdgcn_mfma_f32_16x16x32_bf16(bk[ct][0], A0, s, 0, 0, 0); \
        s = __builtin_amdgcn_mfma_f32_16x16x32_bf16(bk[ct][1], A1, s, 0, 0, 0); \
        sc[ct] = s; \
    } \
    bf16x8 ap0, ap1; \
    _Pragma("unroll") \
    for (int ct = 0; ct < 4; ct++) { \
        _Pragma("unroll") \
        for (int r = 0; r < 4; r++) { \
            float p = __builtin_amdgcn_exp2f(sc[ct][r]); \
            if (MASKED) { \
                int kl = (ct>>1)*32 + lq*8 + (ct&1)*4 + r; \
                int ql = w*16 + lr; \
                p = (kl <= ql) ? p : 0.0f; \
            } \
            bf16_t pb = (bf16_t)p; \
            if (ct < 2) ap0[(ct&1)*4 + r] = pb; \
            else        ap1[(ct&1)*4 + r] = pb; \
        } \
    } \
    _Pragma("unroll") \
    for (int c = 0; c < 4; c++) { \
        ACC[c] = __builtin_amdgcn_mfma_f32_16x16x32_bf16(ap0, bv[c][0], ACC[c], 0, 0, 0); \
        ACC[c] = __builtin_amdgcn_mfma_f32_16x16x32_bf16(ap1, bv[c][1], ACC[c], 0, 0, 0); \
    } \
    AL = __builtin_amdgcn_mfma_f32_16x16x32_bf16(ap0, ones, AL, 0, 0, 0); \
    AL = __builtin_amdgcn_mfma_f32_16x16x32_bf16(ap1, ones, AL, 0, 0, 0); \
} while (0)

#define AITER(KSC, VSC, KSN, VSN, T) do { \
    __syncthreads(); \
    if ((T) + 1 < nIter) ASTAGE(KSN, VSN, ((T)+1)*64); \
    bf16x8 bk[4][2], bv[4][2]; \
    const int sw = lr & 7; \
    _Pragma("unroll") \
    for (int ct = 0; ct < 4; ct++) { \
        int row = ct*16 + lr; \
        bk[ct][0] = *(const bf16x8*)(&KSC[row*64 + ((lq    ) ^ sw)*8]); \
        bk[ct][1] = *(const bf16x8*)(&KSC[row*64 + ((lq + 4) ^ sw)*8]); \
        bv[ct][0] = *(const bf16x8*)(&VSC[row*64 + ((lq    ) ^ sw)*8]); \
        bv[ct][1] = *(const bf16x8*)(&VSC[row*64 + ((lq + 4) ^ sw)*8]); \
    } \
    if ((T) < nIter - 1) { \
        if ((T) == nIter - 2) { STRIP(aqA0, aqA1, accA, alA, true); } \
        else                  { STRIP(aqA0, aqA1, accA, alA, false); } \
    } \
    if ((T) == nIter - 1) { STRIP(aqB0, aqB1, accB, alB, true); } \
    else                  { STRIP(aqB0, aqB1, accB, alB, false); } \
} while (0)

__global__ __launch_bounds__(256, 3) void attn(
    const bf16_t* __restrict__ Q, const bf16_t* __restrict__ K,
    const bf16_t* __restrict__ VT, bf16_t* __restrict__ O)
{
    __shared__ bf16_t Ks0[64*64];
    __shared__ bf16_t Vs0[64*64];
    __shared__ bf16_t Ks1[64*64];
    __shared__ bf16_t Vs1[64*64];

    // --- balanced (bh, qt2) assignment from flat block id ---
    const int n = blockIdx.x;            // 0..767
    const int k = n >> 8;                // co-residency slot 0..2
    const int m = n & 255;
    const int x = m & 7;                 // XCD lane; bh % 8 == x
    const int r = (m >> 3) & 15;         // triple row
    const int cp = (m >> 3) >> 4;        // copy 0/1
    const uint64_t tq = (k == 0) ? 0xABBBCCCDDDEEEFFFull
                      : (k == 1) ? 0x989A87A679568567ull
                                 : 0x5431331420420210ull;
    const uint32_t rk = (k == 0) ? 0xA4924924u
                      : (k == 1) ? 0xA5624500u
                                 : 0xAA45A140u;
    const int qt2 = (int)((tq >> (r * 4)) & 15);             // q-tile 0..15 (128 rows)
    const int bh  = x + 8 * (2 * (int)((rk >> (r * 2)) & 3) + cp);   // 0..47

    const int w = threadIdx.x >> 6, lane = threadIdx.x & 63;
    const int lr = lane & 15, lq = lane >> 4;
    const int qsA = qt2*128 + w*16;
    const int qsB = qsA + 64;
    const int srow = lane >> 3;              // 0..7
    const int g    = (lane & 7) ^ srow;      // XOR-swizzled chunk to fetch

    const bf16_t* Qp = Q  + (size_t)bh*SEQ*DK;
    const bf16_t* Kp = K  + (size_t)bh*SEQ*DK;
    const bf16_t* Vp = VT + (size_t)bh*DK*SEQ;

    const bf16x8 aqA0 = *(const bf16x8*)(Qp + (size_t)(qsA+lr)*DK + lq*8);
    const bf16x8 aqA1 = *(const bf16x8*)(Qp + (size_t)(qsA+lr)*DK + 32 + lq*8);
    const bf16x8 aqB0 = *(const bf16x8*)(Qp + (size_t)(qsB+lr)*DK + lq*8);
    const bf16x8 aqB1 = *(const bf16x8*)(Qp + (size_t)(qsB+lr)*DK + 32 + lq*8);

    bf16x8 ones;
    #pragma unroll
    for (int i = 0; i < 8; i++) ones[i] = (bf16_t)1.0f;

    f32x4 accA[4] = {}, accB[4] = {};
    f32x4 alA = {}, alB = {};

    const int nIter = 2*qt2 + 2;         // 2..32, block-uniform

    ASTAGE(Ks0, Vs0, 0);
    int t = 0;
    while (true) {
        AITER(Ks0, Vs0, Ks1, Vs1, t); t++;
        if (t >= nIter) break;
        AITER(Ks1, Vs1, Ks0, Vs0, t); t++;
        if (t >= nIter) break;
    }

    const int b = bh / NH, h = bh % NH;
    #pragma unroll
    for (int r2 = 0; r2 < 4; r2++) {
        float rlA = 1.0f / alA[r2];
        float rlB = 1.0f / alB[r2];
        int qa = qsA + lq*4 + r2;
        int qb = qsB + lq*4 + r2;
        bf16_t* opA = O + (size_t)(b*SEQ + qa)*DMODEL + h*DK;
        bf16_t* opB = O + (size_t)(b*SEQ + qb)*DMODEL + h*DK;
        #pragma unroll
        for (int c = 0; c < 4; c++) {
            opA[c*16 + lr] = (bf16_t)(accA[c][r2] * rlA);
            opB[c*16 + lr] = (bf16_t)(accB[c][r2] * rlB);
        }
    }
}

extern "C" void kernel_launch(void* const* d_in, const int* in_sizes, int n_in,
                              void* d_out, int out_size, void* d_ws, size_t ws_size,
                              hipStream_t stream) {
    const float* x    = (const float*)d_in[0];
    const float* wqkv = (const float*)d_in[1];
    const float* wo   = (const float*)d_in[2];
    float* out = (float*)d_out;

    char* ws = (char*)d_ws;
    const size_t SZ_X   = (size_t)NTOK*DMODEL*2;
    const size_t SZ_WQ  = (size_t)3*DMODEL*DMODEL*2;
    const size_t SZ_WO  = (size_t)DMODEL*DMODEL*2;
    const size_t SZ_HD  = (size_t)NB*NH*SEQ*DK*2;
    bf16_t* xb    = (bf16_t*)(ws);
    bf16_t* wqkvb = (bf16_t*)(ws + SZ_X);
    bf16_t* wob   = (bf16_t*)(ws + SZ_X + SZ_WQ);
    bf16_t* Qb    = (bf16_t*)(ws + SZ_X + SZ_WQ + SZ_WO);
    bf16_t* Kb    = (bf16_t*)(ws + SZ_X + SZ_WQ + SZ_WO + SZ_HD);
    bf16_t* VTb   = (bf16_t*)(ws + SZ_X + SZ_WQ + SZ_WO + 2*SZ_HD);
    bf16_t* Ob    = (bf16_t*)(ws + SZ_X + SZ_WQ + SZ_WO + 3*SZ_HD);

    cvt_all<<<(N_X4 + N_WQ4 + N_WO4) / 256, 256, 0, stream>>>(x, wqkv, wo, xb);

    gemm_qkv<<<dim3(NTOK/128, 3*DMODEL/192), 256, 0, stream>>>(xb, wqkvb, Qb, Kb, VTb);
    attn<<<768, 256, 0, stream>>>(Qb, Kb, VTb, Ob);
    gemm_oproj<<<dim3(NTOK/128, DMODEL/64), 256, 0, stream>>>(Ob, wob, out);
}

// Round 6
// 177.155 us; speedup vs baseline: 1.0869x; 1.0869x over previous
//
#include <hip/hip_runtime.h>
#include <hip/hip_bf16.h>
#include <stdint.h>

#define SEQ 2048
#define NB 4
#define NH 12
#define DMODEL 768
#define DK 64
#define NTOK (NB*SEQ)          // 8192
#define QSCALE 0.18033688011f  // 0.125 * log2(e)

#define N_X4   (NTOK*DMODEL/4)          // 1572864
#define N_WQ4  (3*DMODEL*DMODEL/4)      // 442368
#define N_WO4  (DMODEL*DMODEL/4)        // 147456

typedef __bf16 bf16_t;
typedef __attribute__((ext_vector_type(4))) bf16_t bf16x4;
typedef __attribute__((ext_vector_type(8))) bf16_t bf16x8;
typedef __attribute__((ext_vector_type(4))) float f32x4;

typedef __attribute__((address_space(3))) uint32_t lds_u32_t;
typedef const __attribute__((address_space(1))) uint32_t glb_u32_t;

__device__ inline void load_lds16(const void* g, void* l) {
    __builtin_amdgcn_global_load_lds((glb_u32_t*)g, (lds_u32_t*)l, 16, 0, 0);
}

// ---------------- fp32 -> bf16 convert (x, wqkv, wo fused; dst regions contiguous) ----------------
__global__ void cvt_all(const float* __restrict__ x, const float* __restrict__ wq,
                        const float* __restrict__ wo, bf16_t* __restrict__ dst) {
    int i = blockIdx.x * blockDim.x + threadIdx.x;   // grid sized exactly
    const float* src; int off;
    if (i < N_X4)              { src = x;  off = i; }
    else if (i < N_X4 + N_WQ4) { src = wq; off = i - N_X4; }
    else                       { src = wo; off = i - (N_X4 + N_WQ4); }
    float4 v = ((const float4*)src)[off];
    bf16x4 o;
    o[0] = (bf16_t)v.x; o[1] = (bf16_t)v.y; o[2] = (bf16_t)v.z; o[3] = (bf16_t)v.w;
    ((bf16x4*)dst)[i] = o;
}

// =================== QKV GEMM: 128x192 tile, BK=32, dbuf, R13 line-pair XOR-swizzled LDS ===================
// R14 note: bank conflicts measured 0 after the R13 swizzle; dur unchanged -> 2-phase structural
// ceiling (~685 TF) reached; conflicts were hidden under the stage/barrier critical path. Keep as-is.
#define QSTAGE(AS, BS, KB) do { \
    _Pragma("unroll") \
    for (int j = 0; j < 5; j++) { \
        int c = tid + j*256; \
        if (c < 512) { \
            int row = c >> 2, cb = ((c & 3) ^ ((c >> 3) & 3)) * 8; \
            load_lds16(Ap_ + (size_t)(mt*128 + row)*DMODEL + (KB) + cb, AS + c*8); \
        } else { \
            int c2 = c - 512; \
            int row = c2 >> 2, cb = ((c2 & 3) ^ ((c2 >> 3) & 3)) * 8; \
            load_lds16(Bp_ + (size_t)(nt*192 + row)*DMODEL + (KB) + cb, BS + c2*8); \
        } \
    } \
} while (0)

#define QCOMPUTE(AS, BS) do { \
    bf16x8 af[4]; \
    _Pragma("unroll") \
    for (int f = 0; f < 4; f++) \
        af[f] = *(const bf16x8*)(AS + (wy*32 + f*8 + lh)*64 + xr); \
    _Pragma("unroll") \
    for (int fn = 0; fn < 6; fn++) { \
        bf16x8 bfr = *(const bf16x8*)(BS + (wx*48 + fn*8 + lh)*64 + xr); \
        _Pragma("unroll") \
        for (int fm = 0; fm < 4; fm++) \
            acc[fm][fn] = __builtin_amdgcn_mfma_f32_16x16x32_bf16(af[fm], bfr, acc[fm][fn], 0, 0, 0); \
    } \
} while (0)

__global__ __launch_bounds__(256, 3) void gemm_qkv(
    const bf16_t* __restrict__ Ap_, const bf16_t* __restrict__ Bp_,
    bf16_t* __restrict__ Qo, bf16_t* __restrict__ Ko, bf16_t* __restrict__ VTo)
{
    __shared__ bf16_t As0[128*32];
    __shared__ bf16_t Bs0[192*32];
    __shared__ bf16_t As1[128*32];
    __shared__ bf16_t Bs1[192*32];
    const int mt = blockIdx.x, nt = blockIdx.y;
    const int tid = threadIdx.x;
    const int w = tid >> 6, lane = tid & 63;
    const int wx = w & 1, wy = w >> 1;
    const int lr = lane & 15, lq = lane >> 4;
    const int lh = lr >> 1;                                  // line index within 16-row group
    const int xr = (lr & 1)*32 + ((lq ^ (lh & 3)) * 8);      // intra-line swizzled elem offset

    f32x4 acc[4][6] = {};
    QSTAGE(As0, Bs0, 0);
    for (int kb = 0; kb < DMODEL; kb += 64) {
        __syncthreads();
        QSTAGE(As1, Bs1, kb + 32);
        QCOMPUTE(As0, Bs0);
        __syncthreads();
        if (kb + 64 < DMODEL) QSTAGE(As0, Bs0, kb + 64);
        QCOMPUTE(As1, Bs1);
    }

    const int t = nt >> 2;                      // 768 = 4*192: tile never spans Q/K/V
    const int ob = (nt & 3) * 192 + wx * 96;    // col base within 768
    if (t == 2) {
        // V: r=0..3 are s-contiguous -> packed b64 stores
        #pragma unroll
        for (int fm = 0; fm < 4; fm++)
            #pragma unroll
            for (int fn = 0; fn < 6; fn++) {
                int m0 = mt*128 + wy*64 + fm*16 + lq*4;
                int o = ob + fn*16 + lr;
                int b = m0 >> 11, s0 = m0 & 2047;
                int h = o >> 6, dk = o & 63;
                bf16x4 v4;
                #pragma unroll
                for (int r = 0; r < 4; r++) v4[r] = (bf16_t)acc[fm][fn][r];
                *(bf16x4*)(VTo + (size_t)((b*NH + h)*DK + dk)*SEQ + s0) = v4;
            }
    } else {
        #pragma unroll
        for (int fm = 0; fm < 4; fm++)
            #pragma unroll
            for (int fn = 0; fn < 6; fn++)
                #pragma unroll
                for (int r = 0; r < 4; r++) {
                    int m = mt*128 + wy*64 + fm*16 + lq*4 + r;
                    int o = ob + fn*16 + lr;
                    int b = m >> 11, s = m & 2047;
                    int h = o >> 6, dk = o & 63;
                    float v = acc[fm][fn][r];
                    if (t == 0) Qo[(size_t)((b*NH + h)*SEQ + s)*DK + dk] = (bf16_t)(v * QSCALE);
                    else        Ko[(size_t)((b*NH + h)*SEQ + s)*DK + dk] = (bf16_t)v;
                }
    }
}

// ---------------- O projection GEMM: 128x64 tile, R13 swizzle, grid (64,12)=768 = 3/CU ----------------
#define OSTAGE(AS, BS, KB) do { \
    _Pragma("unroll") \
    for (int j = 0; j < 3; j++) { \
        int c = tid + j*256; \
        if (c < 512) { \
            int row = c >> 2, cb = ((c & 3) ^ ((c >> 3) & 3)) * 8; \
            load_lds16(Ap_ + (size_t)(mt*128 + row)*DMODEL + (KB) + cb, AS + c*8); \
        } else { \
            int c2 = c - 512; \
            int row = c2 >> 2, cb = ((c2 & 3) ^ ((c2 >> 3) & 3)) * 8; \
            load_lds16(Bp_ + (size_t)(nt*64 + row)*DMODEL + (KB) + cb, BS + c2*8); \
        } \
    } \
} while (0)

#define OCOMPUTE(AS, BS) do { \
    bf16x8 af[4], bfr[2]; \
    _Pragma("unroll") \
    for (int f = 0; f < 4; f++) \
        af[f]  = *(const bf16x8*)(AS + (wy*32 + f*8 + lh)*64 + xr); \
    _Pragma("unroll") \
    for (int f = 0; f < 2; f++) \
        bfr[f] = *(const bf16x8*)(BS + (wx*16 + f*8 + lh)*64 + xr); \
    _Pragma("unroll") \
    for (int fm = 0; fm < 4; fm++) \
        _Pragma("unroll") \
        for (int fn = 0; fn < 2; fn++) \
            acc[fm][fn] = __builtin_amdgcn_mfma_f32_16x16x32_bf16(af[fm], bfr[fn], acc[fm][fn], 0, 0, 0); \
} while (0)

__global__ __launch_bounds__(256, 4) void gemm_oproj(
    const bf16_t* __restrict__ Ap_, const bf16_t* __restrict__ Bp_, float* __restrict__ out)
{
    __shared__ bf16_t As0[128*32];
    __shared__ bf16_t Bs0[64*32];
    __shared__ bf16_t As1[128*32];
    __shared__ bf16_t Bs1[64*32];
    const int mt = blockIdx.x, nt = blockIdx.y;
    const int tid = threadIdx.x;
    const int w = tid >> 6, lane = tid & 63;
    const int wx = w & 1, wy = w >> 1;
    const int lr = lane & 15, lq = lane >> 4;
    const int lh = lr >> 1;
    const int xr = (lr & 1)*32 + ((lq ^ (lh & 3)) * 8);

    f32x4 acc[4][2] = {};
    OSTAGE(As0, Bs0, 0);
    for (int kb = 0; kb < DMODEL; kb += 64) {
        __syncthreads();
        OSTAGE(As1, Bs1, kb + 32);
        OCOMPUTE(As0, Bs0);
        __syncthreads();
        if (kb + 64 < DMODEL) OSTAGE(As0, Bs0, kb + 64);
        OCOMPUTE(As1, Bs1);
    }

    #pragma unroll
    for (int fm = 0; fm < 4; fm++)
        #pragma unroll
        for (int fn = 0; fn < 2; fn++)
            #pragma unroll
            for (int r = 0; r < 4; r++) {
                int m = mt*128 + wy*64 + fm*16 + lq*4 + r;
                int n = nt*64 + wx*32 + fn*16 + lr;
                out[(size_t)m*DMODEL + n] = acc[fm][fn][r];
            }
}

// ---------------- Flash attention (causal) — R16: R13 paired structure + 3-buf counted-vmcnt pipeline ----------------
// R15 lesson: co-resident block RUNTIME uniformity is the controlling variable. R13's pairing gives
// every block exactly 33 strip-units in <=32 iters (qtA early-exit + qtB full) -> all blocks finish
// together; R14/R15 broke that and regressed. R16 keeps R13's paired (qtA, 31-qtA) grid (48,16)=3/CU
// and removes the one remaining structural stall: the per-iter vmcnt(0) drain that __syncthreads
// forced (dbuf reads a buffer staged only ONE iter ago -> drain was genuinely required).
// Fix (catalog T3/T4): TRIPLE-buffer K/V, stage TWO tiles ahead; per iter:
//   {vmcnt(4) [vmcnt(0) on final iter]; s_barrier; sched_barrier(0); stage(t+2); read frags; compute}
// At iter t the 4 newest outstanding loads are stage(t+1)'s -> vmcnt(4) forces stage(t) complete
// without draining the pipeline. Barrier makes all waves' stage(t) visible before reads; stage
// writes (issued after barrier) target buf[(t+2)%3] == buffer read at t-1, whose reads completed
// before the barrier. LDS 48 KB -> still 3 blocks/CU. + T5 setprio(1) around MFMA clusters
// (independent blocks per CU at different phases = role diversity; catalog attn +4-7%).
// K staged with kappa(p) = [p5 p3 p2 p4 p1 p0] so lane (lr,lq)'s 16 score regs are exactly keys
// {lq*8+j} u {32+lq*8+j} = the PV A-fragment octets; P never touches LDS; denominator on MFMA pipe.
// Mask (diagonal): kl = (ct>>1)*32 + lq*8 + (ct&1)*4 + r vs ql = w*16 + lr.
#define ASTAGE(KS, VS, KB) do { \
    _Pragma("unroll") \
    for (int j = 0; j < 2; j++) { \
        int rr = w*16 + j*8 + srow; \
        int kperm = (w>>1)*32 + (j*2 + (srow>>2))*8 + (w&1)*4 + (srow&3);  /* kappa(rr) */ \
        load_lds16(Kp + (size_t)((KB) + kperm)*DK + g*8,  &KS[w*1024 + j*512 + lane*8]); \
        load_lds16(Vp + (size_t)rr*SEQ + (KB) + g*8,   &VS[w*1024 + j*512 + lane*8]); \
    } \
} while (0)

#define STRIP(A0, A1, ACC, AL, MASKED) do { \
    f32x4 sc[4]; \
    __builtin_amdgcn_s_setprio(1); \
    _Pragma("unroll") \
    for (int ct = 0; ct < 4; ct++) { \
        f32x4 s = {}; \
        s = __builtin_amdgcn_mfma_f32_16x16x32_bf16(bk[ct][0], A0, s, 0, 0, 0); \
        s = __builtin_amdgcn_mfma_f32_16x16x32_bf16(bk[ct][1], A1, s, 0, 0, 0); \
        sc[ct] = s; \
    } \
    __builtin_amdgcn_s_setprio(0); \
    bf16x8 ap0, ap1; \
    _Pragma("unroll") \
    for (int ct = 0; ct < 4; ct++) { \
        _Pragma("unroll") \
        for (int r = 0; r < 4; r++) { \
            float p = __builtin_amdgcn_exp2f(sc[ct][r]); \
            if (MASKED) { \
                int kl = (ct>>1)*32 + lq*8 + (ct&1)*4 + r; \
                int ql = w*16 + lr; \
                p = (kl <= ql) ? p : 0.0f; \
            } \
            bf16_t pb = (bf16_t)p; \
            if (ct < 2) ap0[(ct&1)*4 + r] = pb; \
            else        ap1[(ct&1)*4 + r] = pb; \
        } \
    } \
    __builtin_amdgcn_s_setprio(1); \
    _Pragma("unroll") \
    for (int c = 0; c < 4; c++) { \
        ACC[c] = __builtin_amdgcn_mfma_f32_16x16x32_bf16(ap0, bv[c][0], ACC[c], 0, 0, 0); \
        ACC[c] = __builtin_amdgcn_mfma_f32_16x16x32_bf16(ap1, bv[c][1], ACC[c], 0, 0, 0); \
    } \
    AL = __builtin_amdgcn_mfma_f32_16x16x32_bf16(ap0, ones, AL, 0, 0, 0); \
    AL = __builtin_amdgcn_mfma_f32_16x16x32_bf16(ap1, ones, AL, 0, 0, 0); \
    __builtin_amdgcn_s_setprio(0); \
} while (0)

#define AITER(KSC, VSC, KSS, VSS, T) do { \
    if ((T) == nIter - 1) { asm volatile("s_waitcnt vmcnt(0)" ::: "memory"); } \
    else                  { asm volatile("s_waitcnt vmcnt(4)" ::: "memory"); } \
    __builtin_amdgcn_s_barrier(); \
    __builtin_amdgcn_sched_barrier(0); \
    if ((T) + 2 < nIter) ASTAGE(KSS, VSS, ((T)+2)*64); \
    bf16x8 bk[4][2], bv[4][2]; \
    const int sw = lr & 7; \
    _Pragma("unroll") \
    for (int ct = 0; ct < 4; ct++) { \
        int row = ct*16 + lr; \
        bk[ct][0] = *(const bf16x8*)(&KSC[row*64 + ((lq    ) ^ sw)*8]); \
        bk[ct][1] = *(const bf16x8*)(&KSC[row*64 + ((lq + 4) ^ sw)*8]); \
        bv[ct][0] = *(const bf16x8*)(&VSC[row*64 + ((lq    ) ^ sw)*8]); \
        bv[ct][1] = *(const bf16x8*)(&VSC[row*64 + ((lq + 4) ^ sw)*8]); \
    } \
    if ((T) <= qtA) { \
        if ((T) == qtA) { STRIP(aqA0, aqA1, accA, alA, true); } \
        else            { STRIP(aqA0, aqA1, accA, alA, false); } \
    } \
    if ((T) == nIter - 1) { STRIP(aqB0, aqB1, accB, alB, true); } \
    else                  { STRIP(aqB0, aqB1, accB, alB, false); } \
} while (0)

__global__ __launch_bounds__(256, 3) void attn(
    const bf16_t* __restrict__ Q, const bf16_t* __restrict__ K,
    const bf16_t* __restrict__ VT, bf16_t* __restrict__ O)
{
    __shared__ bf16_t Ks0[64*64];
    __shared__ bf16_t Vs0[64*64];
    __shared__ bf16_t Ks1[64*64];
    __shared__ bf16_t Vs1[64*64];
    __shared__ bf16_t Ks2[64*64];
    __shared__ bf16_t Vs2[64*64];

    const int bh  = blockIdx.x;          // 0..47  -> XCD = bh % 8
    const int qtA = blockIdx.y;          // 0..15
    const int qtB = 31 - qtA;            // 16..31
    const int w = threadIdx.x >> 6, lane = threadIdx.x & 63;
    const int lr = lane & 15, lq = lane >> 4;
    const int qsA = qtA*64 + w*16;
    const int qsB = qtB*64 + w*16;
    const int srow = lane >> 3;              // 0..7
    const int g    = (lane & 7) ^ srow;      // XOR-swizzled chunk to fetch

    const bf16_t* Qp = Q  + (size_t)bh*SEQ*DK;
    const bf16_t* Kp = K  + (size_t)bh*SEQ*DK;
    const bf16_t* Vp = VT + (size_t)bh*DK*SEQ;

    const bf16x8 aqA0 = *(const bf16x8*)(Qp + (size_t)(qsA+lr)*DK + lq*8);
    const bf16x8 aqA1 = *(const bf16x8*)(Qp + (size_t)(qsA+lr)*DK + 32 + lq*8);
    const bf16x8 aqB0 = *(const bf16x8*)(Qp + (size_t)(qsB+lr)*DK + lq*8);
    const bf16x8 aqB1 = *(const bf16x8*)(Qp + (size_t)(qsB+lr)*DK + 32 + lq*8);

    bf16x8 ones;
    #pragma unroll
    for (int i = 0; i < 8; i++) ones[i] = (bf16_t)1.0f;

    f32x4 accA[4] = {}, accB[4] = {};
    f32x4 alA = {}, alB = {};

    const int nIter = 32 - qtA;          // 17..32, block-uniform

    ASTAGE(Ks0, Vs0, 0);
    ASTAGE(Ks1, Vs1, 64);
    int t = 0;
    while (true) {
        AITER(Ks0, Vs0, Ks2, Vs2, t); t++;
        if (t >= nIter) break;
        AITER(Ks1, Vs1, Ks0, Vs0, t); t++;
        if (t >= nIter) break;
        AITER(Ks2, Vs2, Ks1, Vs1, t); t++;
        if (t >= nIter) break;
    }

    const int b = bh / NH, h = bh % NH;
    #pragma unroll
    for (int r = 0; r < 4; r++) {
        float rlA = 1.0f / alA[r];
        float rlB = 1.0f / alB[r];
        int qa = qsA + lq*4 + r;
        int qb = qsB + lq*4 + r;
        bf16_t* opA = O + (size_t)(b*SEQ + qa)*DMODEL + h*DK;
        bf16_t* opB = O + (size_t)(b*SEQ + qb)*DMODEL + h*DK;
        #pragma unroll
        for (int c = 0; c < 4; c++) {
            opA[c*16 + lr] = (bf16_t)(accA[c][r] * rlA);
            opB[c*16 + lr] = (bf16_t)(accB[c][r] * rlB);
        }
    }
}

extern "C" void kernel_launch(void* const* d_in, const int* in_sizes, int n_in,
                              void* d_out, int out_size, void* d_ws, size_t ws_size,
                              hipStream_t stream) {
    const float* x    = (const float*)d_in[0];
    const float* wqkv = (const float*)d_in[1];
    const float* wo   = (const float*)d_in[2];
    float* out = (float*)d_out;

    char* ws = (char*)d_ws;
    const size_t SZ_X   = (size_t)NTOK*DMODEL*2;
    const size_t SZ_WQ  = (size_t)3*DMODEL*DMODEL*2;
    const size_t SZ_WO  = (size_t)DMODEL*DMODEL*2;
    const size_t SZ_HD  = (size_t)NB*NH*SEQ*DK*2;
    bf16_t* xb    = (bf16_t*)(ws);
    bf16_t* wqkvb = (bf16_t*)(ws + SZ_X);
    bf16_t* wob   = (bf16_t*)(ws + SZ_X + SZ_WQ);
    bf16_t* Qb    = (bf16_t*)(ws + SZ_X + SZ_WQ + SZ_WO);
    bf16_t* Kb    = (bf16_t*)(ws + SZ_X + SZ_WQ + SZ_WO + SZ_HD);
    bf16_t* VTb   = (bf16_t*)(ws + SZ_X + SZ_WQ + SZ_WO + 2*SZ_HD);
    bf16_t* Ob    = (bf16_t*)(ws + SZ_X + SZ_WQ + SZ_WO + 3*SZ_HD);

    cvt_all<<<(N_X4 + N_WQ4 + N_WO4) / 256, 256, 0, stream>>>(x, wqkv, wo, xb);

    gemm_qkv<<<dim3(NTOK/128, 3*DMODEL/192), 256, 0, stream>>>(xb, wqkvb, Qb, Kb, VTb);
    attn<<<dim3(NB*NH, 16), 256, 0, stream>>>(Qb, Kb, VTb, Ob);
    gemm_oproj<<<dim3(NTOK/128, DMODEL/64), 256, 0, stream>>>(Ob, wob, out);
}

// Round 7
// 170.285 us; speedup vs baseline: 1.1308x; 1.0403x over previous
//
#include <hip/hip_runtime.h>
#include <hip/hip_bf16.h>
#include <stdint.h>

#define SEQ 2048
#define NB 4
#define NH 12
#define DMODEL 768
#define DK 64
#define NTOK (NB*SEQ)          // 8192
#define QSCALE 0.18033688011f  // 0.125 * log2(e)

#define N_X4   (NTOK*DMODEL/4)          // 1572864
#define N_WQ4  (3*DMODEL*DMODEL/4)      // 442368
#define N_WO4  (DMODEL*DMODEL/4)        // 147456

typedef __bf16 bf16_t;
typedef __attribute__((ext_vector_type(4))) bf16_t bf16x4;
typedef __attribute__((ext_vector_type(8))) bf16_t bf16x8;
typedef __attribute__((ext_vector_type(4))) float f32x4;

typedef __attribute__((address_space(3))) uint32_t lds_u32_t;
typedef const __attribute__((address_space(1))) uint32_t glb_u32_t;

__device__ inline void load_lds16(const void* g, void* l) {
    __builtin_amdgcn_global_load_lds((glb_u32_t*)g, (lds_u32_t*)l, 16, 0, 0);
}

// ---------------- fp32 -> bf16 convert (x, wqkv, wo fused; dst regions contiguous) ----------------
__global__ void cvt_all(const float* __restrict__ x, const float* __restrict__ wq,
                        const float* __restrict__ wo, bf16_t* __restrict__ dst) {
    int i = blockIdx.x * blockDim.x + threadIdx.x;   // grid sized exactly
    const float* src; int off;
    if (i < N_X4)              { src = x;  off = i; }
    else if (i < N_X4 + N_WQ4) { src = wq; off = i - N_X4; }
    else                       { src = wo; off = i - (N_X4 + N_WQ4); }
    float4 v = ((const float4*)src)[off];
    bf16x4 o;
    o[0] = (bf16_t)v.x; o[1] = (bf16_t)v.y; o[2] = (bf16_t)v.z; o[3] = (bf16_t)v.w;
    ((bf16x4*)dst)[i] = o;
}

// =================== QKV GEMM: 128x192 tile, BK=32, dbuf, R13 line-pair XOR-swizzled LDS ===================
// R14 note: bank conflicts 0 after the R13 swizzle; 2-phase structural ceiling reached. Keep as-is.
#define QSTAGE(AS, BS, KB) do { \
    _Pragma("unroll") \
    for (int j = 0; j < 5; j++) { \
        int c = tid + j*256; \
        if (c < 512) { \
            int row = c >> 2, cb = ((c & 3) ^ ((c >> 3) & 3)) * 8; \
            load_lds16(Ap_ + (size_t)(mt*128 + row)*DMODEL + (KB) + cb, AS + c*8); \
        } else { \
            int c2 = c - 512; \
            int row = c2 >> 2, cb = ((c2 & 3) ^ ((c2 >> 3) & 3)) * 8; \
            load_lds16(Bp_ + (size_t)(nt*192 + row)*DMODEL + (KB) + cb, BS + c2*8); \
        } \
    } \
} while (0)

#define QCOMPUTE(AS, BS) do { \
    bf16x8 af[4]; \
    _Pragma("unroll") \
    for (int f = 0; f < 4; f++) \
        af[f] = *(const bf16x8*)(AS + (wy*32 + f*8 + lh)*64 + xr); \
    _Pragma("unroll") \
    for (int fn = 0; fn < 6; fn++) { \
        bf16x8 bfr = *(const bf16x8*)(BS + (wx*48 + fn*8 + lh)*64 + xr); \
        _Pragma("unroll") \
        for (int fm = 0; fm < 4; fm++) \
            acc[fm][fn] = __builtin_amdgcn_mfma_f32_16x16x32_bf16(af[fm], bfr, acc[fm][fn], 0, 0, 0); \
    } \
} while (0)

__global__ __launch_bounds__(256, 3) void gemm_qkv(
    const bf16_t* __restrict__ Ap_, const bf16_t* __restrict__ Bp_,
    bf16_t* __restrict__ Qo, bf16_t* __restrict__ Ko, bf16_t* __restrict__ VTo)
{
    __shared__ bf16_t As0[128*32];
    __shared__ bf16_t Bs0[192*32];
    __shared__ bf16_t As1[128*32];
    __shared__ bf16_t Bs1[192*32];
    const int mt = blockIdx.x, nt = blockIdx.y;
    const int tid = threadIdx.x;
    const int w = tid >> 6, lane = tid & 63;
    const int wx = w & 1, wy = w >> 1;
    const int lr = lane & 15, lq = lane >> 4;
    const int lh = lr >> 1;                                  // line index within 16-row group
    const int xr = (lr & 1)*32 + ((lq ^ (lh & 3)) * 8);      // intra-line swizzled elem offset

    f32x4 acc[4][6] = {};
    QSTAGE(As0, Bs0, 0);
    for (int kb = 0; kb < DMODEL; kb += 64) {
        __syncthreads();
        QSTAGE(As1, Bs1, kb + 32);
        QCOMPUTE(As0, Bs0);
        __syncthreads();
        if (kb + 64 < DMODEL) QSTAGE(As0, Bs0, kb + 64);
        QCOMPUTE(As1, Bs1);
    }

    const int t = nt >> 2;                      // 768 = 4*192: tile never spans Q/K/V
    const int ob = (nt & 3) * 192 + wx * 96;    // col base within 768
    if (t == 2) {
        // V: r=0..3 are s-contiguous -> packed b64 stores
        #pragma unroll
        for (int fm = 0; fm < 4; fm++)
            #pragma unroll
            for (int fn = 0; fn < 6; fn++) {
                int m0 = mt*128 + wy*64 + fm*16 + lq*4;
                int o = ob + fn*16 + lr;
                int b = m0 >> 11, s0 = m0 & 2047;
                int h = o >> 6, dk = o & 63;
                bf16x4 v4;
                #pragma unroll
                for (int r = 0; r < 4; r++) v4[r] = (bf16_t)acc[fm][fn][r];
                *(bf16x4*)(VTo + (size_t)((b*NH + h)*DK + dk)*SEQ + s0) = v4;
            }
    } else {
        #pragma unroll
        for (int fm = 0; fm < 4; fm++)
            #pragma unroll
            for (int fn = 0; fn < 6; fn++)
                #pragma unroll
                for (int r = 0; r < 4; r++) {
                    int m = mt*128 + wy*64 + fm*16 + lq*4 + r;
                    int o = ob + fn*16 + lr;
                    int b = m >> 11, s = m & 2047;
                    int h = o >> 6, dk = o & 63;
                    float v = acc[fm][fn][r];
                    if (t == 0) Qo[(size_t)((b*NH + h)*SEQ + s)*DK + dk] = (bf16_t)(v * QSCALE);
                    else        Ko[(size_t)((b*NH + h)*SEQ + s)*DK + dk] = (bf16_t)v;
                }
    }
}

// ---------------- O projection GEMM: 128x64 tile, R13 swizzle, grid (64,12)=768 = 3/CU ----------------
// R17 change: A is now read from the head-major O buffer [b][h][s][dk] (attn writes it coalesced).
// k = h*64+dk keeps the SAME k-ordering as the old [b][s][h*64+dk] layout, and a 32-elem k-chunk
// never crosses an h boundary (32 | 64), so only the A staging address changes — granularity,
// swizzle, wo staging and the output are untouched.
#define OSTAGE(AS, BS, KB) do { \
    _Pragma("unroll") \
    for (int j = 0; j < 3; j++) { \
        int c = tid + j*256; \
        if (c < 512) { \
            int row = c >> 2, cb = ((c & 3) ^ ((c >> 3) & 3)) * 8; \
            int m = mt*128 + row; \
            int kk = (KB) + cb; \
            load_lds16(Ap_ + ((size_t)((m >> 11)*NH + (kk >> 6))*SEQ + (m & 2047))*DK + (kk & 63), AS + c*8); \
        } else { \
            int c2 = c - 512; \
            int row = c2 >> 2, cb = ((c2 & 3) ^ ((c2 >> 3) & 3)) * 8; \
            load_lds16(Bp_ + (size_t)(nt*64 + row)*DMODEL + (KB) + cb, BS + c2*8); \
        } \
    } \
} while (0)

#define OCOMPUTE(AS, BS) do { \
    bf16x8 af[4], bfr[2]; \
    _Pragma("unroll") \
    for (int f = 0; f < 4; f++) \
        af[f]  = *(const bf16x8*)(AS + (wy*32 + f*8 + lh)*64 + xr); \
    _Pragma("unroll") \
    for (int f = 0; f < 2; f++) \
        bfr[f] = *(const bf16x8*)(BS + (wx*16 + f*8 + lh)*64 + xr); \
    _Pragma("unroll") \
    for (int fm = 0; fm < 4; fm++) \
        _Pragma("unroll") \
        for (int fn = 0; fn < 2; fn++) \
            acc[fm][fn] = __builtin_amdgcn_mfma_f32_16x16x32_bf16(af[fm], bfr[fn], acc[fm][fn], 0, 0, 0); \
} while (0)

__global__ __launch_bounds__(256, 4) void gemm_oproj(
    const bf16_t* __restrict__ Ap_, const bf16_t* __restrict__ Bp_, float* __restrict__ out)
{
    __shared__ bf16_t As0[128*32];
    __shared__ bf16_t Bs0[64*32];
    __shared__ bf16_t As1[128*32];
    __shared__ bf16_t Bs1[64*32];
    const int mt = blockIdx.x, nt = blockIdx.y;
    const int tid = threadIdx.x;
    const int w = tid >> 6, lane = tid & 63;
    const int wx = w & 1, wy = w >> 1;
    const int lr = lane & 15, lq = lane >> 4;
    const int lh = lr >> 1;
    const int xr = (lr & 1)*32 + ((lq ^ (lh & 3)) * 8);

    f32x4 acc[4][2] = {};
    OSTAGE(As0, Bs0, 0);
    for (int kb = 0; kb < DMODEL; kb += 64) {
        __syncthreads();
        OSTAGE(As1, Bs1, kb + 32);
        OCOMPUTE(As0, Bs0);
        __syncthreads();
        if (kb + 64 < DMODEL) OSTAGE(As0, Bs0, kb + 64);
        OCOMPUTE(As1, Bs1);
    }

    #pragma unroll
    for (int fm = 0; fm < 4; fm++)
        #pragma unroll
        for (int fn = 0; fn < 2; fn++)
            #pragma unroll
            for (int r = 0; r < 4; r++) {
                int m = mt*128 + wy*64 + fm*16 + lq*4 + r;
                int n = nt*64 + wx*32 + fn*16 + lr;
                out[(size_t)m*DMODEL + n] = acc[fm][fn][r];
            }
}

// ---------------- Flash attention (causal) — R17: R13 structure restored + head-major O writes ----------------
// R16 post-mortem: the counted-vmcnt/setprio graft on this 2-buffer loop REGRESSED (42.2->47.4 µs)
// — consistent with the catalog's "T3/T4/T5 null-as-graft" evidence; the implicit 12-wave/CU
// overlap already covered the drain. R13's loop core is the proven local optimum: paired
// (qtA, 31-qtA) grid (48,16)=3/CU (every block = exactly 33 strip-units -> uniform finish),
// swapped QK^T with kappa-permuted K staging (zero-LDS P), denominator on the MFMA pipe,
// __syncthreads dbuf. Restored verbatim.
// R17 change: O is written head-major [b][h][s][dk] (consumed by gemm_oproj with matching
// addressing). Old layout scattered 32-B shards at 1536-B stride -> write-allocate amplification
// (attn WRITE_SIZE 22-30 MB vs 12.6 ideal). Now each (lq,r) row's 64 elems = one full 128-B line,
// 16 consecutive lines per wave strip. Mask (diagonal): kl = (ct>>1)*32 + lq*8 + (ct&1)*4 + r
// vs ql = w*16 + lr.
#define ASTAGE(KS, VS, KB) do { \
    _Pragma("unroll") \
    for (int j = 0; j < 2; j++) { \
        int rr = w*16 + j*8 + srow; \
        int kperm = (w>>1)*32 + (j*2 + (srow>>2))*8 + (w&1)*4 + (srow&3);  /* kappa(rr) */ \
        load_lds16(Kp + (size_t)((KB) + kperm)*DK + g*8,  &KS[w*1024 + j*512 + lane*8]); \
        load_lds16(Vp + (size_t)rr*SEQ + (KB) + g*8,   &VS[w*1024 + j*512 + lane*8]); \
    } \
} while (0)

#define STRIP(A0, A1, ACC, AL, MASKED) do { \
    f32x4 sc[4]; \
    _Pragma("unroll") \
    for (int ct = 0; ct < 4; ct++) { \
        f32x4 s = {}; \
        s = __builtin_amdgcn_mfma_f32_16x16x32_bf16(bk[ct][0], A0, s, 0, 0, 0); \
        s = __builtin_amdgcn_mfma_f32_16x16x32_bf16(bk[ct][1], A1, s, 0, 0, 0); \
        sc[ct] = s; \
    } \
    bf16x8 ap0, ap1; \
    _Pragma("unroll") \
    for (int ct = 0; ct < 4; ct++) { \
        _Pragma("unroll") \
        for (int r = 0; r < 4; r++) { \
            float p = __builtin_amdgcn_exp2f(sc[ct][r]); \
            if (MASKED) { \
                int kl = (ct>>1)*32 + lq*8 + (ct&1)*4 + r; \
                int ql = w*16 + lr; \
                p = (kl <= ql) ? p : 0.0f; \
            } \
            bf16_t pb = (bf16_t)p; \
            if (ct < 2) ap0[(ct&1)*4 + r] = pb; \
            else        ap1[(ct&1)*4 + r] = pb; \
        } \
    } \
    _Pragma("unroll") \
    for (int c = 0; c < 4; c++) { \
        ACC[c] = __builtin_amdgcn_mfma_f32_16x16x32_bf16(ap0, bv[c][0], ACC[c], 0, 0, 0); \
        ACC[c] = __builtin_amdgcn_mfma_f32_16x16x32_bf16(ap1, bv[c][1], ACC[c], 0, 0, 0); \
    } \
    AL = __builtin_amdgcn_mfma_f32_16x16x32_bf16(ap0, ones, AL, 0, 0, 0); \
    AL = __builtin_amdgcn_mfma_f32_16x16x32_bf16(ap1, ones, AL, 0, 0, 0); \
} while (0)

#define AITER(KSC, VSC, KSN, VSN, T) do { \
    __syncthreads(); \
    if ((T) + 1 < nIter) ASTAGE(KSN, VSN, ((T)+1)*64); \
    bf16x8 bk[4][2], bv[4][2]; \
    const int sw = lr & 7; \
    _Pragma("unroll") \
    for (int ct = 0; ct < 4; ct++) { \
        int row = ct*16 + lr; \
        bk[ct][0] = *(const bf16x8*)(&KSC[row*64 + ((lq    ) ^ sw)*8]); \
        bk[ct][1] = *(const bf16x8*)(&KSC[row*64 + ((lq + 4) ^ sw)*8]); \
        bv[ct][0] = *(const bf16x8*)(&VSC[row*64 + ((lq    ) ^ sw)*8]); \
        bv[ct][1] = *(const bf16x8*)(&VSC[row*64 + ((lq + 4) ^ sw)*8]); \
    } \
    if ((T) <= qtA) { \
        if ((T) == qtA) { STRIP(aqA0, aqA1, accA, alA, true); } \
        else            { STRIP(aqA0, aqA1, accA, alA, false); } \
    } \
    if ((T) == nIter - 1) { STRIP(aqB0, aqB1, accB, alB, true); } \
    else                  { STRIP(aqB0, aqB1, accB, alB, false); } \
} while (0)

__global__ __launch_bounds__(256, 3) void attn(
    const bf16_t* __restrict__ Q, const bf16_t* __restrict__ K,
    const bf16_t* __restrict__ VT, bf16_t* __restrict__ O)
{
    __shared__ bf16_t Ks0[64*64];
    __shared__ bf16_t Vs0[64*64];
    __shared__ bf16_t Ks1[64*64];
    __shared__ bf16_t Vs1[64*64];

    const int bh  = blockIdx.x;          // 0..47  -> XCD = bh % 8
    const int qtA = blockIdx.y;          // 0..15
    const int qtB = 31 - qtA;            // 16..31
    const int w = threadIdx.x >> 6, lane = threadIdx.x & 63;
    const int lr = lane & 15, lq = lane >> 4;
    const int qsA = qtA*64 + w*16;
    const int qsB = qtB*64 + w*16;
    const int srow = lane >> 3;              // 0..7
    const int g    = (lane & 7) ^ srow;      // XOR-swizzled chunk to fetch

    const bf16_t* Qp = Q  + (size_t)bh*SEQ*DK;
    const bf16_t* Kp = K  + (size_t)bh*SEQ*DK;
    const bf16_t* Vp = VT + (size_t)bh*DK*SEQ;

    const bf16x8 aqA0 = *(const bf16x8*)(Qp + (size_t)(qsA+lr)*DK + lq*8);
    const bf16x8 aqA1 = *(const bf16x8*)(Qp + (size_t)(qsA+lr)*DK + 32 + lq*8);
    const bf16x8 aqB0 = *(const bf16x8*)(Qp + (size_t)(qsB+lr)*DK + lq*8);
    const bf16x8 aqB1 = *(const bf16x8*)(Qp + (size_t)(qsB+lr)*DK + 32 + lq*8);

    bf16x8 ones;
    #pragma unroll
    for (int i = 0; i < 8; i++) ones[i] = (bf16_t)1.0f;

    f32x4 accA[4] = {}, accB[4] = {};
    f32x4 alA = {}, alB = {};

    const int nIter = 32 - qtA;          // 17..32, block-uniform

    ASTAGE(Ks0, Vs0, 0);
    int t = 0;
    while (true) {
        AITER(Ks0, Vs0, Ks1, Vs1, t); t++;
        if (t >= nIter) break;
        AITER(Ks1, Vs1, Ks0, Vs0, t); t++;
        if (t >= nIter) break;
    }

    // Head-major O: [b][h][s][dk] — each (lq,r) row writes one full 128-B line.
    #pragma unroll
    for (int r = 0; r < 4; r++) {
        float rlA = 1.0f / alA[r];
        float rlB = 1.0f / alB[r];
        int qa = qsA + lq*4 + r;
        int qb = qsB + lq*4 + r;
        bf16_t* opA = O + ((size_t)bh*SEQ + qa)*DK;
        bf16_t* opB = O + ((size_t)bh*SEQ + qb)*DK;
        #pragma unroll
        for (int c = 0; c < 4; c++) {
            opA[c*16 + lr] = (bf16_t)(accA[c][r] * rlA);
            opB[c*16 + lr] = (bf16_t)(accB[c][r] * rlB);
        }
    }
}

extern "C" void kernel_launch(void* const* d_in, const int* in_sizes, int n_in,
                              void* d_out, int out_size, void* d_ws, size_t ws_size,
                              hipStream_t stream) {
    const float* x    = (const float*)d_in[0];
    const float* wqkv = (const float*)d_in[1];
    const float* wo   = (const float*)d_in[2];
    float* out = (float*)d_out;

    char* ws = (char*)d_ws;
    const size_t SZ_X   = (size_t)NTOK*DMODEL*2;
    const size_t SZ_WQ  = (size_t)3*DMODEL*DMODEL*2;
    const size_t SZ_WO  = (size_t)DMODEL*DMODEL*2;
    const size_t SZ_HD  = (size_t)NB*NH*SEQ*DK*2;
    bf16_t* xb    = (bf16_t*)(ws);
    bf16_t* wqkvb = (bf16_t*)(ws + SZ_X);
    bf16_t* wob   = (bf16_t*)(ws + SZ_X + SZ_WQ);
    bf16_t* Qb    = (bf16_t*)(ws + SZ_X + SZ_WQ + SZ_WO);
    bf16_t* Kb    = (bf16_t*)(ws + SZ_X + SZ_WQ + SZ_WO + SZ_HD);
    bf16_t* VTb   = (bf16_t*)(ws + SZ_X + SZ_WQ + SZ_WO + 2*SZ_HD);
    bf16_t* Ob    = (bf16_t*)(ws + SZ_X + SZ_WQ + SZ_WO + 3*SZ_HD);   // head-major [b][h][s][dk]

    cvt_all<<<(N_X4 + N_WQ4 + N_WO4) / 256, 256, 0, stream>>>(x, wqkv, wo, xb);

    gemm_qkv<<<dim3(NTOK/128, 3*DMODEL/192), 256, 0, stream>>>(xb, wqkvb, Qb, Kb, VTb);
    attn<<<dim3(NB*NH, 16), 256, 0, stream>>>(Qb, Kb, VTb, Ob);
    gemm_oproj<<<dim3(NTOK/128, DMODEL/64), 256, 0, stream>>>(Ob, wob, out);
}